// Round 6
// baseline (991.939 us; speedup 1.0000x reference)
//
#include <hip/hip_runtime.h>
#include <hip/hip_bf16.h>

// ---------------------------------------------------------------------------
// ProjectedConjugatedCSPNet: LN -> edge MLP (gather+sinemb+2xGEMM+silu) ->
// scatter-mean -> node MLP (2xGEMM+silu) -> residual add.
// R6: restructured edge_mlp K-pipeline. Double 64x520 slab (136KB LDS,
//     1 block/CU, launch_bounds(512,2) -> 256-VGPR budget). Both gathers
//     DMA'd up-front (one latency exposure); sin/cos staging interleaved
//     into the previous kloop (VALU co-issues with MFMA); kloop register-
//     pipelined: A-frags +1 ktile, B-frags +2 ktiles, full unroll,
//     per-call-site slab instantiation for exact LDS aliasing.
// ---------------------------------------------------------------------------

#include <type_traits>

typedef __attribute__((ext_vector_type(8))) short bfrag;   // 8 bf16 = 4 VGPRs
typedef __attribute__((ext_vector_type(4))) float ffrag;   // 4 fp32 acc

#define DEVI __device__ __forceinline__

constexpr int N_NODES = 10000;
constexpr int N_EDGES = 200000;
constexpr int HD      = 512;     // hidden dim
constexpr int KE      = 1824;    // padded edge-K: 512 hi + 512 hj + 32 lat(pad) + 384 sin + 384 cos
constexpr int NT      = HD / 16; // 32 n-tiles of 16 cols
constexpr int SLABW   = 520;     // slab row stride in ushorts (1040 B)
constexpr int KSTR    = NT * 64 * 8;  // B ktile stride in ushorts (16384)

template <int N> using IC = std::integral_constant<int, N>;

DEVI float silu_f(float v) { return v / (1.0f + __expf(-v)); }

DEVI ushort f2bf(float f) {
    unsigned u = __float_as_uint(f);
    unsigned r = (u + 0x7fffu + ((u >> 16) & 1u)) >> 16;
    return (ushort)r;
}
DEVI float bf2f(ushort v) { return __uint_as_float((unsigned)v << 16); }

DEVI void gll16(const ushort* gp, ushort* lp) {
    // global -> LDS DMA, 16B/lane. LDS side = wave-uniform base + lane*16;
    // global side is per-lane addressed (gather-capable).
    __builtin_amdgcn_global_load_lds((const __attribute__((address_space(1))) void*)gp,
                                     (__attribute__((address_space(3))) void*)lp, 16, 0, 0);
}

// ---------------- LayerNorm: node_features -> h (bf16) ----------------------
__global__ void ln_kernel(const float* __restrict__ x, const float* __restrict__ g,
                          const float* __restrict__ b, ushort* __restrict__ h) {
    __shared__ float wred[8];
    __shared__ float mb[2];
    int row = blockIdx.x;
    int t = threadIdx.x;              // 256 threads
    const float* xr = x + (size_t)row * HD;
    float x0 = xr[t], x1 = xr[t + 256];
    float s = x0 + x1, q = x0 * x0 + x1 * x1;
    for (int o = 32; o; o >>= 1) { s += __shfl_down(s, o); q += __shfl_down(q, o); }
    int w = t >> 6, l = t & 63;
    if (l == 0) { wred[w] = s; wred[w + 4] = q; }
    __syncthreads();
    if (t == 0) {
        float S = wred[0] + wred[1] + wred[2] + wred[3];
        float Q = wred[4] + wred[5] + wred[6] + wred[7];
        float m = S * (1.0f / HD);
        float v = Q * (1.0f / HD) - m * m;
        mb[0] = m; mb[1] = rsqrtf(v + 1e-5f);
    }
    __syncthreads();
    float m = mb[0], rs = mb[1];
    h[(size_t)row * HD + t]       = f2bf((x0 - m) * rs * g[t] + b[t]);
    h[(size_t)row * HD + t + 256] = f2bf((x1 - m) * rs * g[t + 256] + b[t + 256]);
}

// ------- Weight swizzle: W[K x 512] fp32 -> B-fragment-linear bf16 ----------
__global__ void wswz_kernel(const float* __restrict__ W, ushort* __restrict__ dst,
                            int Kp, int mode) {
    int fid = blockIdx.x * blockDim.x + threadIdx.x;
    int total = (Kp / 32) * NT * 64;
    if (fid >= total) return;
    int l  = fid & 63;
    int nn = (fid >> 6) & 31;
    int kk = fid >> 11;
    int col = nn * 16 + (l & 15);
    int kb  = kk * 32 + (l >> 4) * 8;
    union { ushort u16[8]; uint4 u4; } v;
    for (int j = 0; j < 8; ++j) {
        int krow = kb + j;
        int src;
        if (mode == 1) {
            if (krow < 1024)      src = krow;                            // hi | hj
            else if (krow < 1056) src = (krow - 1024) < 6 ? krow : -1;   // lat (pad->0)
            else                  src = krow - 26;                       // sin|cos: 1030 + (krow-1056)
        } else {
            src = krow;
        }
        float f = (src < 0) ? 0.0f : W[(size_t)src * HD + col];
        v.u16[j] = f2bf(f);
    }
    *(uint4*)(dst + (size_t)fid * 8) = v.u4;
}

// ---------------- CSR build -------------------------------------------------
__global__ void hist_kernel(const int* __restrict__ eidx, int* __restrict__ cnt32) {
    int e = blockIdx.x * 256 + threadIdx.x;
    if (e < N_EDGES) atomicAdd(&cnt32[eidx[e]], 1);
}

__global__ void scan_kernel(const int* __restrict__ cnt32, int* __restrict__ row_ptr,
                            int* __restrict__ cursor) {
    __shared__ int buf[1024];
    int t = threadIdx.x;              // 1024 threads
    int base = t * 10;
    int loc[10]; int s = 0;
    for (int i = 0; i < 10; ++i) {
        int idx = base + i;
        int v = (idx < N_NODES) ? cnt32[idx] : 0;
        loc[i] = s; s += v;
    }
    buf[t] = s; __syncthreads();
    for (int off = 1; off < 1024; off <<= 1) {
        int v = 0; if (t >= off) v = buf[t - off];
        __syncthreads();
        buf[t] += v; __syncthreads();
    }
    int excl = buf[t] - s;            // exclusive prefix
    for (int i = 0; i < 10; ++i) {
        int idx = base + i;
        if (idx < N_NODES) { int p = excl + loc[i]; row_ptr[idx] = p; cursor[idx] = p; }
    }
    if (t == 0) row_ptr[N_NODES] = N_EDGES;
}

__global__ void csr_fill(const int* __restrict__ eidx, int* __restrict__ cursor,
                         int* __restrict__ ebuf) {
    int e = blockIdx.x * 256 + threadIdx.x;
    if (e >= N_EDGES) return;
    int pos = atomicAdd(&cursor[eidx[e]], 1);
    ebuf[pos] = e;
}

// ---------------- agg (fp32) / deg -> aggb (bf16) ---------------------------
__global__ void aggdiv_kernel(const float* __restrict__ agg, const int* __restrict__ rp,
                              ushort* __restrict__ aggb) {
    int i = blockIdx.x * 256 + threadIdx.x;
    int row = i >> 9;
    int deg = rp[row + 1] - rp[row];
    float rc = 1.0f / (float)max(deg, 1);
    aggb[i] = f2bf(agg[i] * rc);
}

__global__ void sentinel_kernel(float* o, int n) {
    int i = blockIdx.x * 256 + threadIdx.x;
    if (i < n) o[i] = 123456789.0f;
}

// ---------------- Fused edge MLP, pipelined (64 edges x 512 cols/block) -----
__global__ __launch_bounds__(512, 2) void edge_mlp(
    const ushort* __restrict__ h,     const ushort* __restrict__ w1s,
    const ushort* __restrict__ w2s,   const float* __restrict__ b1,
    const float* __restrict__ b2,     float* __restrict__ agg,
    const int* __restrict__ edge_index, const int* __restrict__ e2g,
    const float* __restrict__ lattices, const float* __restrict__ frac_diff,
    const int* __restrict__ ebuf) {

    __shared__ __align__(16) ushort slabA[64 * SLABW];    // 66560 B
    __shared__ __align__(16) ushort slabB[64 * SLABW];    // 66560 B
    __shared__ int   ssrc[64];
    __shared__ int   sdst[64];
    __shared__ float sfd[64 * 3];
    __shared__ float slat[64 * 6];

    const int t = threadIdx.x;        // 512 threads = 8 waves
    const int w = t >> 6;
    const int l = t & 63;
    const int q = l >> 4;
    const int ml = l & 15;
    const int rowbase = blockIdx.x * 64;

    if (t < 64) {
        int eid = ebuf[rowbase + t];
        ssrc[t] = edge_index[eid];
        sdst[t] = edge_index[N_EDGES + eid];
        int g = e2g[eid];
        for (int c = 0; c < 6; ++c) slat[t * 6 + c] = lattices[g * 6 + c];
        for (int c = 0; c < 3; ++c) sfd[t * 3 + c] = frac_diff[(size_t)eid * 3 + c];
    }
    __syncthreads();

    // ---- DMA both gathers up-front: hi -> slabA, hj -> slabB ----
    for (int j = 0; j < 8; ++j) {
        int r = w * 8 + j;
        gll16(h + (size_t)ssrc[r] * HD + l * 8, &slabA[r * SLABW]);
    }
    for (int j = 0; j < 8; ++j) {
        int r = w * 8 + j;
        gll16(h + (size_t)sdst[r] * HD + l * 8, &slabB[r * SLABW]);
    }

    ffrag acc[4][4];
    for (int m = 0; m < 4; ++m)
        for (int n = 0; n < 4; ++n)
            acc[m][n] = (ffrag){0.0f, 0.0f, 0.0f, 0.0f};

    const int r  = t >> 3;            // staging row 0..63
    const int c0 = (t & 7) * 4;       // staging col 0..28 step 4
    float fx = sfd[r * 3 + 0], fy = sfd[r * 3 + 1], fz = sfd[r * 3 + 2];

    // staging lambdas (write target fixed per lambda -> exact LDS aliasing)
    auto stage_latsin = [&](int i) {      // cols 0..415 of slabA = lat|sin
        if (i >= 13) return;
        int c = c0 + 32 * i;
        float f[4];
        if (c < 32) {
            for (int ii = 0; ii < 4; ++ii) {
                int cc = c + ii;
                f[ii] = (cc < 6) ? slat[r * 6 + cc] : 0.0f;
            }
        } else {
            int d = c - 32;                    // 0..383
            int dim = d >> 7;
            float x = (dim == 0) ? fx : (dim == 1) ? fy : fz;
            float base = (float)(d & 127) * x;
            for (int ii = 0; ii < 4; ++ii)
                f[ii] = __builtin_amdgcn_sinf(__builtin_amdgcn_fractf(base + (float)ii * x));
        }
        *(ushort4*)&slabA[r * SLABW + c] = make_ushort4(f2bf(f[0]), f2bf(f[1]), f2bf(f[2]), f2bf(f[3]));
    };
    auto stage_cos = [&](int i) {         // cols 0..383 of slabB = cos
        if (i >= 12) return;
        int c = c0 + 32 * i;
        int dim = c >> 7;
        float x = (dim == 0) ? fx : (dim == 1) ? fy : fz;
        float base = (float)(c & 127) * x;
        float f[4];
        for (int ii = 0; ii < 4; ++ii)
            f[ii] = __builtin_amdgcn_cosf(__builtin_amdgcn_fractf(base + (float)ii * x));
        *(ushort4*)&slabB[r * SLABW + c] = make_ushort4(f2bf(f[0]), f2bf(f[1]), f2bf(f[2]), f2bf(f[3]));
    };
    auto nostage = [&](int) {};

    // Register-pipelined kloop: A-frags prefetched +1 ktile (ds ~120cyc),
    // B-frags +2 ktiles (L2 ~200-400cyc). Full unroll; sl passed as the
    // actual array so the compiler sees slabA/slabB as distinct objects.
    auto kloop = [&](auto ntc, const ushort* Bswz, int gbase, auto& sl, auto stage) {
        constexpr int NTILES = decltype(ntc)::value;
        const ushort* bp = Bswz + ((size_t)(gbase * NT + (w << 2)) * 64 + l) * 8;
        bfrag a_[2][4], b_[3][4];
        #pragma unroll
        for (int n = 0; n < 4; ++n) b_[0][n] = *(const bfrag*)(bp + n * 512);
        #pragma unroll
        for (int n = 0; n < 4; ++n) b_[1][n] = *(const bfrag*)(bp + KSTR + n * 512);
        #pragma unroll
        for (int m = 0; m < 4; ++m) a_[0][m] = *(const bfrag*)&sl[(16 * m + ml) * SLABW + q * 8];
        #pragma unroll
        for (int p = 0; p < NTILES; ++p) {
            if (p + 2 < NTILES) {
                const ushort* bpn = bp + (size_t)(p + 2) * KSTR;
                #pragma unroll
                for (int n = 0; n < 4; ++n) b_[(p + 2) % 3][n] = *(const bfrag*)(bpn + n * 512);
            }
            if (p + 1 < NTILES) {
                #pragma unroll
                for (int m = 0; m < 4; ++m)
                    a_[(p + 1) & 1][m] = *(const bfrag*)&sl[(16 * m + ml) * SLABW + (p + 1) * 32 + q * 8];
            }
            #pragma unroll
            for (int m = 0; m < 4; ++m)
                #pragma unroll
                for (int n = 0; n < 4; ++n)
                    acc[m][n] = __builtin_amdgcn_mfma_f32_16x16x32_bf16(a_[p & 1][m], b_[p % 3][n], acc[m][n], 0, 0, 0);
            stage(p);
        }
    };

    __syncthreads();                              // both DMA slabs ready (one drain)

    kloop(IC<16>{}, w1s, 0,  slabA, nostage);
    __syncthreads();                              // slabA free
    kloop(IC<16>{}, w1s, 16, slabB, stage_latsin);  // stage lat+sin -> slabA while computing hj
    __syncthreads();                              // slabA(lat+sin) ready, slabB free
    kloop(IC<13>{}, w1s, 32, slabA, stage_cos);     // stage cos -> slabB while computing lat+sin
    __syncthreads();                              // slabB(cos) ready; slabA readers done
    kloop(IC<12>{}, w1s, 45, slabB, nostage);

    // ---- e1 = silu(acc + b1) -> slabA (bf16, row-major); reset acc ----
    for (int n = 0; n < 4; ++n) {
        int cg = w * 64 + n * 16 + ml;
        float bv = b1[cg];
        for (int m = 0; m < 4; ++m)
            for (int rr = 0; rr < 4; ++rr) {
                int rowl = 16 * m + 4 * q + rr;
                slabA[rowl * SLABW + cg] = f2bf(silu_f(acc[m][n][rr] + bv));
            }
    }
    for (int m = 0; m < 4; ++m)
        for (int n = 0; n < 4; ++n)
            acc[m][n] = (ffrag){0.0f, 0.0f, 0.0f, 0.0f};
    __syncthreads();                              // e1 complete

    // ---- GEMM2 straight from slabA ----
    kloop(IC<16>{}, w2s, 0, slabA, nostage);

    // ---- silu + CSR run-length segment reduce -> atomic agg (slabB scratch) ----
    float* fs = (float*)slabB;                    // 64 x 256 fp32 = 65536 B
    for (int hh = 0; hh < 2; ++hh) {
        __syncthreads();
        if ((w >> 2) == hh) {
            for (int n = 0; n < 4; ++n) {
                int cg = w * 64 + n * 16 + ml;
                int lc = cg - hh * 256;
                float bv = b2[cg];
                for (int m = 0; m < 4; ++m)
                    for (int rr = 0; rr < 4; ++rr) {
                        int rowl = 16 * m + 4 * q + rr;
                        fs[rowl * 256 + lc] = silu_f(acc[m][n][rr] + bv);
                    }
            }
        }
        __syncthreads();
        if (t < 256) {
            int col = hh * 256 + t;
            int cur = ssrc[0];
            float run = 0.f;
            for (int rr2 = 0; rr2 < 64; ++rr2) {
                int nd = ssrc[rr2];
                if (nd != cur) {
                    unsafeAtomicAdd(&agg[(size_t)cur * HD + col], run);
                    run = 0.f; cur = nd;
                }
                run += fs[rr2 * 256 + t];
            }
            unsafeAtomicAdd(&agg[(size_t)cur * HD + col], run);
        }
    }
}

// ---------------- Fused node MLP (64 nodes x 512 cols per block) ------------
__global__ __launch_bounds__(512, 4) void node_mlp(
    const ushort* __restrict__ h,     const ushort* __restrict__ aggb,
    const ushort* __restrict__ wn1s,  const ushort* __restrict__ wn2s,
    const float* __restrict__ b1,     const float* __restrict__ b2,
    const float* __restrict__ nf,     float* __restrict__ out) {

    __shared__ __align__(16) ushort slab[64 * SLABW];

    const int t = threadIdx.x;        // 512 threads = 8 waves
    const int w = t >> 6;
    const int l = t & 63;
    const int q = l >> 4;
    const int ml = l & 15;
    const int rowbase = blockIdx.x * 64;

    ffrag acc[4][4];
    for (int m = 0; m < 4; ++m)
        for (int n = 0; n < 4; ++n)
            acc[m][n] = (ffrag){0.0f, 0.0f, 0.0f, 0.0f};

    auto load_rows_lin = [&](const ushort* base) {
        for (int j = 0; j < 8; ++j) {
            int r = w * 8 + j;
            int row = rowbase + r;
            if (row >= N_NODES) row = N_NODES - 1;
            const ushort* gp = base + (size_t)row * HD + l * 8;
            gll16(gp, &slab[r * SLABW]);
        }
    };
    auto kloop = [&](const ushort* Bswz, int ntiles, int gbase) {
        for (int p = 0; p < ntiles; ++p) {
            bfrag af[4];
            for (int m = 0; m < 4; ++m)
                af[m] = *(const bfrag*)&slab[(16 * m + ml) * SLABW + p * 32 + q * 8];
            bfrag bf_[4];
            const ushort* bp = Bswz + ((size_t)((gbase + p) * NT + (w << 2)) * 64 + l) * 8;
            for (int n = 0; n < 4; ++n)
                bf_[n] = *(const bfrag*)(bp + (size_t)n * 64 * 8);
            for (int m = 0; m < 4; ++m)
                for (int n = 0; n < 4; ++n)
                    acc[m][n] = __builtin_amdgcn_mfma_f32_16x16x32_bf16(af[m], bf_[n], acc[m][n], 0, 0, 0);
        }
    };

    load_rows_lin(h);                    __syncthreads();
    kloop(wn1s, 16, 0);                  __syncthreads();
    load_rows_lin(aggb);                 __syncthreads();
    kloop(wn1s, 16, 16);                 __syncthreads();

    // o1 = silu(acc + b1) -> slab
    for (int n = 0; n < 4; ++n) {
        int cg = w * 64 + n * 16 + ml;
        float bv = b1[cg];
        for (int m = 0; m < 4; ++m)
            for (int rr = 0; rr < 4; ++rr) {
                int rowl = 16 * m + 4 * q + rr;
                slab[rowl * SLABW + cg] = f2bf(silu_f(acc[m][n][rr] + bv));
            }
    }
    for (int m = 0; m < 4; ++m)
        for (int n = 0; n < 4; ++n)
            acc[m][n] = (ffrag){0.0f, 0.0f, 0.0f, 0.0f};
    __syncthreads();

    kloop(wn2s, 16, 0);

    for (int n = 0; n < 4; ++n) {
        int cg = w * 64 + n * 16 + ml;
        float bv = b2[cg];
        for (int m = 0; m < 4; ++m)
            for (int rr = 0; rr < 4; ++rr) {
                int rowl = 16 * m + 4 * q + rr;
                int row = rowbase + rowl;
                if (row < N_NODES) {
                    float v = silu_f(acc[m][n][rr] + bv);
                    out[(size_t)row * HD + cg] = nf[(size_t)row * HD + cg] + v;
                }
            }
    }
}

// ---------------------------------------------------------------------------
extern "C" void kernel_launch(void* const* d_in, const int* in_sizes, int n_in,
                              void* d_out, int out_size, void* d_ws, size_t ws_size,
                              hipStream_t stream) {
    const float* nf      = (const float*)d_in[0];
    const float* latt    = (const float*)d_in[1];
    const int*   eidx    = (const int*)d_in[2];
    const int*   e2g     = (const int*)d_in[3];
    const float* fd      = (const float*)d_in[4];
    const float* ln_g    = (const float*)d_in[6];
    const float* ln_b    = (const float*)d_in[7];
    const float* W_e1    = (const float*)d_in[8];
    const float* b_e1    = (const float*)d_in[9];
    const float* W_e2    = (const float*)d_in[10];
    const float* b_e2    = (const float*)d_in[11];
    const float* W_n1    = (const float*)d_in[12];
    const float* b_n1    = (const float*)d_in[13];
    const float* W_n2    = (const float*)d_in[14];
    const float* b_n2    = (const float*)d_in[15];
    float* out = (float*)d_out;

    auto al = [](size_t x) { return (x + 511) & ~(size_t)511; };
    size_t off_h    = 0;                         size_t sz_h    = (size_t)N_NODES * HD * 2;
    size_t off_w1   = al(off_h + sz_h);          size_t sz_w1   = (size_t)KE * HD * 2;
    size_t off_w2   = al(off_w1 + sz_w1);        size_t sz_w2   = (size_t)HD * HD * 2;
    size_t off_wn1  = al(off_w2 + sz_w2);        size_t sz_wn1  = (size_t)2 * HD * HD * 2;
    size_t off_wn2  = al(off_wn1 + sz_wn1);      size_t sz_wn2  = (size_t)HD * HD * 2;
    size_t off_agb  = al(off_wn2 + sz_wn2);      size_t sz_agb  = (size_t)N_NODES * HD * 2;
    size_t off_c32  = al(off_agb + sz_agb);      size_t sz_c32  = (size_t)N_NODES * 4;
    size_t off_cur  = al(off_c32 + sz_c32);      size_t sz_cur  = (size_t)N_NODES * 4;
    size_t off_rp   = al(off_cur + sz_cur);      size_t sz_rp   = (size_t)(N_NODES + 1) * 4;
    size_t off_ebuf = al(off_rp + sz_rp);        size_t sz_ebuf = (size_t)N_EDGES * 4;
    size_t off_agg  = al(off_ebuf + sz_ebuf);    size_t sz_agg  = (size_t)N_NODES * HD * 4;
    size_t need     = off_agg + sz_agg;

    if (ws_size < need) {
        sentinel_kernel<<<(out_size + 255) / 256, 256, 0, stream>>>(out, out_size);
        return;
    }

    char* ws = (char*)d_ws;
    ushort* h    = (ushort*)(ws + off_h);
    ushort* w1s  = (ushort*)(ws + off_w1);
    ushort* w2s  = (ushort*)(ws + off_w2);
    ushort* wn1s = (ushort*)(ws + off_wn1);
    ushort* wn2s = (ushort*)(ws + off_wn2);
    ushort* aggb = (ushort*)(ws + off_agb);
    int*    c32  = (int*)(ws + off_c32);
    int*    cur  = (int*)(ws + off_cur);
    int*    rp   = (int*)(ws + off_rp);
    int*    ebuf = (int*)(ws + off_ebuf);
    float*  agg  = (float*)(ws + off_agg);

    // prep
    ln_kernel<<<N_NODES, 256, 0, stream>>>(nf, ln_g, ln_b, h);
    wswz_kernel<<<(KE / 32) * NT * 64 / 256, 256, 0, stream>>>(W_e1, w1s, KE, 1);
    wswz_kernel<<<(HD / 32) * NT * 64 / 256, 256, 0, stream>>>(W_e2, w2s, HD, 0);
    wswz_kernel<<<(2 * HD / 32) * NT * 64 / 256, 256, 0, stream>>>(W_n1, wn1s, 2 * HD, 0);
    wswz_kernel<<<(HD / 32) * NT * 64 / 256, 256, 0, stream>>>(W_n2, wn2s, HD, 0);
    hipMemsetAsync(c32, 0, sz_c32, stream);
    hipMemsetAsync(agg, 0, sz_agg, stream);

    // CSR build (edges sorted by src node)
    hist_kernel<<<(N_EDGES + 255) / 256, 256, 0, stream>>>(eidx, c32);
    scan_kernel<<<1, 1024, 0, stream>>>(c32, rp, cur);
    csr_fill<<<(N_EDGES + 255) / 256, 256, 0, stream>>>(eidx, cur, ebuf);

    // fused edge MLP (CSR order) -> agg
    edge_mlp<<<N_EDGES / 64, 512, 0, stream>>>(
        h, w1s, w2s, b_e1, b_e2, agg, eidx, e2g, latt, fd, ebuf);

    // scatter-mean divide (deg from CSR)
    aggdiv_kernel<<<(N_NODES * HD) / 256, 256, 0, stream>>>(agg, rp, aggb);

    // fused node MLP
    int nblocks = (N_NODES + 63) / 64;
    node_mlp<<<nblocks, 512, 0, stream>>>(h, aggb, wn1s, wn2s, b_n1, b_n2, nf, out);
}

// Round 7
// 665.861 us; speedup vs baseline: 1.4897x; 1.4897x over previous
//
#include <hip/hip_runtime.h>
#include <hip/hip_bf16.h>

// ---------------------------------------------------------------------------
// ProjectedConjugatedCSPNet: LN -> edge MLP (gather+sinemb+2xGEMM+silu) ->
// scatter-mean -> node MLP (2xGEMM+silu) -> residual add.
// R7: algebraic hoist. The hi|hj half of edge-GEMM1 (K=1024 of 1824) is
//     node-level: HA=h*W1a, HB=h*W1b precomputed once (10.7 GFLOP vs 206
//     recomputed per-edge). edge_mlp acc-inits from gathered HA[src]+HB[dst]
//     and only runs K=800 (lat|sin|cos) + GEMM2: 41 ktiles/wave vs 73.
//     Structure otherwise = R5 (single 68KB slab, 2 blocks/CU, simple kloop,
//     CSR segment-reduce epilogue) — R6 showed 1-block/CU pipelining loses.
// ---------------------------------------------------------------------------

typedef __attribute__((ext_vector_type(8))) short bfrag;   // 8 bf16 = 4 VGPRs
typedef __attribute__((ext_vector_type(4))) float ffrag;   // 4 fp32 acc

#define DEVI __device__ __forceinline__

constexpr int N_NODES = 10000;
constexpr int N_EDGES = 200000;
constexpr int HD      = 512;     // hidden dim
constexpr int NT      = HD / 16; // 32 n-tiles of 16 cols
constexpr int SLABW   = 520;     // slab row stride in ushorts (1040 B)
constexpr int KC      = 800;     // edge K-loop: 32 lat(pad) + 384 sin + 384 cos

DEVI float silu_f(float v) { return v / (1.0f + __expf(-v)); }

DEVI ushort f2bf(float f) {
    unsigned u = __float_as_uint(f);
    unsigned r = (u + 0x7fffu + ((u >> 16) & 1u)) >> 16;
    return (ushort)r;
}
DEVI float bf2f(ushort v) { return __uint_as_float((unsigned)v << 16); }

DEVI void gll16(const ushort* gp, ushort* lp) {
    // global -> LDS DMA, 16B/lane. LDS side = wave-uniform base + lane*16;
    // global side is per-lane addressed (gather-capable).
    __builtin_amdgcn_global_load_lds((const __attribute__((address_space(1))) void*)gp,
                                     (__attribute__((address_space(3))) void*)lp, 16, 0, 0);
}

// ---------------- LayerNorm: node_features -> h (bf16) ----------------------
__global__ void ln_kernel(const float* __restrict__ x, const float* __restrict__ g,
                          const float* __restrict__ b, ushort* __restrict__ h) {
    __shared__ float wred[8];
    __shared__ float mb[2];
    int row = blockIdx.x;
    int t = threadIdx.x;              // 256 threads
    const float* xr = x + (size_t)row * HD;
    float x0 = xr[t], x1 = xr[t + 256];
    float s = x0 + x1, q = x0 * x0 + x1 * x1;
    for (int o = 32; o; o >>= 1) { s += __shfl_down(s, o); q += __shfl_down(q, o); }
    int w = t >> 6, l = t & 63;
    if (l == 0) { wred[w] = s; wred[w + 4] = q; }
    __syncthreads();
    if (t == 0) {
        float S = wred[0] + wred[1] + wred[2] + wred[3];
        float Q = wred[4] + wred[5] + wred[6] + wred[7];
        float m = S * (1.0f / HD);
        float v = Q * (1.0f / HD) - m * m;
        mb[0] = m; mb[1] = rsqrtf(v + 1e-5f);
    }
    __syncthreads();
    float m = mb[0], rs = mb[1];
    h[(size_t)row * HD + t]       = f2bf((x0 - m) * rs * g[t] + b[t]);
    h[(size_t)row * HD + t + 256] = f2bf((x1 - m) * rs * g[t + 256] + b[t + 256]);
}

// ------- Weight swizzle: W[K x 512] fp32 -> B-fragment-linear bf16 ----------
// mode 0: identity rows. mode 2: w1c remap onto K=800 [lat32pad|sin384|cos384]
// (W_e1 row space: lat=1024..1029, sin=1030..1413, cos=1414..1797).
__global__ void wswz_kernel(const float* __restrict__ W, ushort* __restrict__ dst,
                            int Kp, int mode) {
    int fid = blockIdx.x * blockDim.x + threadIdx.x;
    int total = (Kp / 32) * NT * 64;
    if (fid >= total) return;
    int l  = fid & 63;
    int nn = (fid >> 6) & 31;
    int kk = fid >> 11;
    int col = nn * 16 + (l & 15);
    int kb  = kk * 32 + (l >> 4) * 8;
    union { ushort u16[8]; uint4 u4; } v;
    for (int j = 0; j < 8; ++j) {
        int krow = kb + j;
        int src;
        if (mode == 2) {
            if (krow < 32)       src = (krow < 6) ? 1024 + krow : -1;
            else if (krow < 416) src = 1030 + (krow - 32);
            else                 src = 1414 + (krow - 416);
        } else {
            src = krow;
        }
        float f = (src < 0) ? 0.0f : W[(size_t)src * HD + col];
        v.u16[j] = f2bf(f);
    }
    *(uint4*)(dst + (size_t)fid * 8) = v.u4;
}

// ---------------- CSR build -------------------------------------------------
__global__ void hist_kernel(const int* __restrict__ eidx, int* __restrict__ cnt32) {
    int e = blockIdx.x * 256 + threadIdx.x;
    if (e < N_EDGES) atomicAdd(&cnt32[eidx[e]], 1);
}

__global__ void scan_kernel(const int* __restrict__ cnt32, int* __restrict__ row_ptr,
                            int* __restrict__ cursor) {
    __shared__ int buf[1024];
    int t = threadIdx.x;              // 1024 threads
    int base = t * 10;
    int loc[10]; int s = 0;
    for (int i = 0; i < 10; ++i) {
        int idx = base + i;
        int v = (idx < N_NODES) ? cnt32[idx] : 0;
        loc[i] = s; s += v;
    }
    buf[t] = s; __syncthreads();
    for (int off = 1; off < 1024; off <<= 1) {
        int v = 0; if (t >= off) v = buf[t - off];
        __syncthreads();
        buf[t] += v; __syncthreads();
    }
    int excl = buf[t] - s;            // exclusive prefix
    for (int i = 0; i < 10; ++i) {
        int idx = base + i;
        if (idx < N_NODES) { int p = excl + loc[i]; row_ptr[idx] = p; cursor[idx] = p; }
    }
    if (t == 0) row_ptr[N_NODES] = N_EDGES;
}

__global__ void csr_fill(const int* __restrict__ eidx, int* __restrict__ cursor,
                         int* __restrict__ ebuf) {
    int e = blockIdx.x * 256 + threadIdx.x;
    if (e >= N_EDGES) return;
    int pos = atomicAdd(&cursor[eidx[e]], 1);
    ebuf[pos] = e;
}

// ---------------- agg (fp32) / deg -> aggb (bf16) ---------------------------
__global__ void aggdiv_kernel(const float* __restrict__ agg, const int* __restrict__ rp,
                              ushort* __restrict__ aggb) {
    int i = blockIdx.x * 256 + threadIdx.x;
    int row = i >> 9;
    int deg = rp[row + 1] - rp[row];
    float rc = 1.0f / (float)max(deg, 1);
    aggb[i] = f2bf(agg[i] * rc);
}

__global__ void sentinel_kernel(float* o, int n) {
    int i = blockIdx.x * 256 + threadIdx.x;
    if (i < n) o[i] = 123456789.0f;
}

// ---------------- plain GEMM: HA = h*W1a, HB = h*W1b (grid.y selects) -------
__global__ __launch_bounds__(512, 4) void hab_gemm(
    const ushort* __restrict__ h, const ushort* __restrict__ w1a_s,
    const ushort* __restrict__ w1b_s, ushort* __restrict__ HA,
    ushort* __restrict__ HB) {

    __shared__ __align__(16) ushort slab[64 * SLABW];
    const int t = threadIdx.x;
    const int w = t >> 6;
    const int l = t & 63;
    const int q = l >> 4;
    const int ml = l & 15;
    const int rowbase = blockIdx.x * 64;
    const ushort* Bswz = blockIdx.y ? w1b_s : w1a_s;
    ushort* out = blockIdx.y ? HB : HA;

    ffrag acc[4][4];
    for (int m = 0; m < 4; ++m)
        for (int n = 0; n < 4; ++n)
            acc[m][n] = (ffrag){0.0f, 0.0f, 0.0f, 0.0f};

    for (int j = 0; j < 8; ++j) {
        int r = w * 8 + j;
        int row = rowbase + r;
        if (row >= N_NODES) row = N_NODES - 1;
        gll16(h + (size_t)row * HD + l * 8, &slab[r * SLABW]);
    }
    __syncthreads();

    for (int p = 0; p < 16; ++p) {
        bfrag af[4];
        for (int m = 0; m < 4; ++m)
            af[m] = *(const bfrag*)&slab[(16 * m + ml) * SLABW + p * 32 + q * 8];
        bfrag bf_[4];
        const ushort* bp = Bswz + ((size_t)(p * NT + (w << 2)) * 64 + l) * 8;
        for (int n = 0; n < 4; ++n)
            bf_[n] = *(const bfrag*)(bp + (size_t)n * 64 * 8);
        for (int m = 0; m < 4; ++m)
            for (int n = 0; n < 4; ++n)
                acc[m][n] = __builtin_amdgcn_mfma_f32_16x16x32_bf16(af[m], bf_[n], acc[m][n], 0, 0, 0);
    }
    __syncthreads();

    for (int n = 0; n < 4; ++n) {
        int cg = w * 64 + n * 16 + ml;
        for (int m = 0; m < 4; ++m)
            for (int rr = 0; rr < 4; ++rr) {
                int rowl = 16 * m + 4 * q + rr;
                slab[rowl * SLABW + cg] = f2bf(acc[m][n][rr]);
            }
    }
    __syncthreads();
    for (int j = 0; j < 8; ++j) {
        int row = w * 8 + j;
        int grow = rowbase + row;
        if (grow >= N_NODES) break;
        uint4 v = *(const uint4*)&slab[row * SLABW + l * 8];
        *(uint4*)(out + (size_t)grow * HD + l * 8) = v;
    }
}

// ---------------- Fused edge MLP (64 edges x 512 cols per block) ------------
// acc = gather(HA,src) + gather(HB,dst); K-loop only lat|sin|cos (25 ktiles)
// with w1c; silu -> slab -> GEMM2(w2s) -> silu + CSR segment reduce -> agg.
__global__ __launch_bounds__(512, 4) void edge_mlp(
    const ushort* __restrict__ HA,    const ushort* __restrict__ HB,
    const ushort* __restrict__ w1c,   const ushort* __restrict__ w2s,
    const float* __restrict__ b1,     const float* __restrict__ b2,
    float* __restrict__ agg,
    const int* __restrict__ edge_index, const int* __restrict__ e2g,
    const float* __restrict__ lattices, const float* __restrict__ frac_diff,
    const int* __restrict__ ebuf) {

    __shared__ __align__(16) ushort slab[64 * SLABW];     // 66560 B (>= 64*256 fp32)
    __shared__ int   ssrc[64];
    __shared__ int   sdst[64];
    __shared__ float sfd[64 * 3];
    __shared__ float slat[64 * 6];

    const int t = threadIdx.x;        // 512 threads = 8 waves
    const int w = t >> 6;
    const int l = t & 63;
    const int q = l >> 4;
    const int ml = l & 15;
    const int rowbase = blockIdx.x * 64;

    if (t < 64) {
        int eid = ebuf[rowbase + t];
        ssrc[t] = edge_index[eid];
        sdst[t] = edge_index[N_EDGES + eid];
        int g = e2g[eid];
        for (int c = 0; c < 6; ++c) slat[t * 6 + c] = lattices[g * 6 + c];
        for (int c = 0; c < 3; ++c) sfd[t * 3 + c] = frac_diff[(size_t)eid * 3 + c];
    }
    __syncthreads();

    ffrag acc[4][4];

    // ---- acc init: HA[src] then HB[dst] through the slab (C-layout reads) ----
    for (int j = 0; j < 8; ++j) {
        int r = w * 8 + j;
        gll16(HA + (size_t)ssrc[r] * HD + l * 8, &slab[r * SLABW]);
    }
    __syncthreads();
    for (int m = 0; m < 4; ++m)
        for (int n = 0; n < 4; ++n) {
            int cg = w * 64 + n * 16 + ml;
            for (int rr = 0; rr < 4; ++rr)
                acc[m][n][rr] = bf2f(slab[(16 * m + 4 * q + rr) * SLABW + cg]);
        }
    __syncthreads();
    for (int j = 0; j < 8; ++j) {
        int r = w * 8 + j;
        gll16(HB + (size_t)sdst[r] * HD + l * 8, &slab[r * SLABW]);
    }
    __syncthreads();
    for (int m = 0; m < 4; ++m)
        for (int n = 0; n < 4; ++n) {
            int cg = w * 64 + n * 16 + ml;
            for (int rr = 0; rr < 4; ++rr)
                acc[m][n][rr] += bf2f(slab[(16 * m + 4 * q + rr) * SLABW + cg]);
        }
    __syncthreads();

    const int r  = t >> 3;            // staging row 0..63
    const int c0 = (t & 7) * 4;       // staging col 0..28 step 4
    float fx = sfd[r * 3 + 0], fy = sfd[r * 3 + 1], fz = sfd[r * 3 + 2];

    auto kloop = [&](const ushort* Bswz, int ntiles, int gbase) {
        for (int p = 0; p < ntiles; ++p) {
            bfrag af[4];
            for (int m = 0; m < 4; ++m)
                af[m] = *(const bfrag*)&slab[(16 * m + ml) * SLABW + p * 32 + q * 8];
            bfrag bf_[4];
            const ushort* bp = Bswz + ((size_t)((gbase + p) * NT + (w << 2)) * 64 + l) * 8;
            for (int n = 0; n < 4; ++n)
                bf_[n] = *(const bfrag*)(bp + (size_t)n * 64 * 8);
            for (int m = 0; m < 4; ++m)
                for (int n = 0; n < 4; ++n)
                    acc[m][n] = __builtin_amdgcn_mfma_f32_16x16x32_bf16(af[m], bf_[n], acc[m][n], 0, 0, 0);
        }
    };

    // ---- phase C1: lat(32 incl pad) + sin(384) = 13 ktiles ----
    for (int i = 0; i < 13; ++i) {
        int c = c0 + 32 * i;
        float f[4];
        if (c < 32) {
            for (int ii = 0; ii < 4; ++ii) {
                int cc = c + ii;
                f[ii] = (cc < 6) ? slat[r * 6 + cc] : 0.0f;
            }
        } else {
            int d = c - 32;                    // 0..383
            int dim = d >> 7;
            float x = (dim == 0) ? fx : (dim == 1) ? fy : fz;
            float base = (float)(d & 127) * x;
            for (int ii = 0; ii < 4; ++ii)
                f[ii] = __builtin_amdgcn_sinf(__builtin_amdgcn_fractf(base + (float)ii * x));
        }
        *(ushort4*)&slab[r * SLABW + c] = make_ushort4(f2bf(f[0]), f2bf(f[1]), f2bf(f[2]), f2bf(f[3]));
    }
    __syncthreads();
    kloop(w1c, 13, 0);
    __syncthreads();

    // ---- phase C2: cos(384) = 12 ktiles ----
    for (int i = 0; i < 12; ++i) {
        int c = c0 + 32 * i;                   // 0..383
        int dim = c >> 7;
        float x = (dim == 0) ? fx : (dim == 1) ? fy : fz;
        float base = (float)(c & 127) * x;
        float f[4];
        for (int ii = 0; ii < 4; ++ii)
            f[ii] = __builtin_amdgcn_cosf(__builtin_amdgcn_fractf(base + (float)ii * x));
        *(ushort4*)&slab[r * SLABW + c] = make_ushort4(f2bf(f[0]), f2bf(f[1]), f2bf(f[2]), f2bf(f[3]));
    }
    __syncthreads();
    kloop(w1c, 12, 13);

    // ---- e1 = silu(acc + b1) -> slab (bf16); reset acc ----
    __syncthreads();
    for (int n = 0; n < 4; ++n) {
        int cg = w * 64 + n * 16 + ml;
        float bv = b1[cg];
        for (int m = 0; m < 4; ++m)
            for (int rr = 0; rr < 4; ++rr) {
                int rowl = 16 * m + 4 * q + rr;
                slab[rowl * SLABW + cg] = f2bf(silu_f(acc[m][n][rr] + bv));
            }
    }
    for (int m = 0; m < 4; ++m)
        for (int n = 0; n < 4; ++n)
            acc[m][n] = (ffrag){0.0f, 0.0f, 0.0f, 0.0f};
    __syncthreads();

    // ---- GEMM2 straight from the slab ----
    kloop(w2s, 16, 0);

    // ---- silu + CSR run-length segment reduce -> atomic agg ----
    float* fs = (float*)slab;            // 64 x 256 fp32 = 65536 B
    for (int hh = 0; hh < 2; ++hh) {
        __syncthreads();
        if ((w >> 2) == hh) {
            for (int n = 0; n < 4; ++n) {
                int cg = w * 64 + n * 16 + ml;
                int lc = cg - hh * 256;
                float bv = b2[cg];
                for (int m = 0; m < 4; ++m)
                    for (int rr = 0; rr < 4; ++rr) {
                        int rowl = 16 * m + 4 * q + rr;
                        fs[rowl * 256 + lc] = silu_f(acc[m][n][rr] + bv);
                    }
            }
        }
        __syncthreads();
        if (t < 256) {
            int col = hh * 256 + t;
            int cur = ssrc[0];
            float run = 0.f;
            for (int rr2 = 0; rr2 < 64; ++rr2) {
                int nd = ssrc[rr2];
                if (nd != cur) {
                    unsafeAtomicAdd(&agg[(size_t)cur * HD + col], run);
                    run = 0.f; cur = nd;
                }
                run += fs[rr2 * 256 + t];
            }
            unsafeAtomicAdd(&agg[(size_t)cur * HD + col], run);
        }
    }
}

// ---------------- Fused node MLP (64 nodes x 512 cols per block) ------------
__global__ __launch_bounds__(512, 4) void node_mlp(
    const ushort* __restrict__ h,     const ushort* __restrict__ aggb,
    const ushort* __restrict__ wn1s,  const ushort* __restrict__ wn2s,
    const float* __restrict__ b1,     const float* __restrict__ b2,
    const float* __restrict__ nf,     float* __restrict__ out) {

    __shared__ __align__(16) ushort slab[64 * SLABW];

    const int t = threadIdx.x;        // 512 threads = 8 waves
    const int w = t >> 6;
    const int l = t & 63;
    const int q = l >> 4;
    const int ml = l & 15;
    const int rowbase = blockIdx.x * 64;

    ffrag acc[4][4];
    for (int m = 0; m < 4; ++m)
        for (int n = 0; n < 4; ++n)
            acc[m][n] = (ffrag){0.0f, 0.0f, 0.0f, 0.0f};

    auto load_rows_lin = [&](const ushort* base) {
        for (int j = 0; j < 8; ++j) {
            int r = w * 8 + j;
            int row = rowbase + r;
            if (row >= N_NODES) row = N_NODES - 1;
            const ushort* gp = base + (size_t)row * HD + l * 8;
            gll16(gp, &slab[r * SLABW]);
        }
    };
    auto kloop = [&](const ushort* Bswz, int ntiles, int gbase) {
        for (int p = 0; p < ntiles; ++p) {
            bfrag af[4];
            for (int m = 0; m < 4; ++m)
                af[m] = *(const bfrag*)&slab[(16 * m + ml) * SLABW + p * 32 + q * 8];
            bfrag bf_[4];
            const ushort* bp = Bswz + ((size_t)((gbase + p) * NT + (w << 2)) * 64 + l) * 8;
            for (int n = 0; n < 4; ++n)
                bf_[n] = *(const bfrag*)(bp + (size_t)n * 64 * 8);
            for (int m = 0; m < 4; ++m)
                for (int n = 0; n < 4; ++n)
                    acc[m][n] = __builtin_amdgcn_mfma_f32_16x16x32_bf16(af[m], bf_[n], acc[m][n], 0, 0, 0);
        }
    };

    load_rows_lin(h);                    __syncthreads();
    kloop(wn1s, 16, 0);                  __syncthreads();
    load_rows_lin(aggb);                 __syncthreads();
    kloop(wn1s, 16, 16);                 __syncthreads();

    // o1 = silu(acc + b1) -> slab
    for (int n = 0; n < 4; ++n) {
        int cg = w * 64 + n * 16 + ml;
        float bv = b1[cg];
        for (int m = 0; m < 4; ++m)
            for (int rr = 0; rr < 4; ++rr) {
                int rowl = 16 * m + 4 * q + rr;
                slab[rowl * SLABW + cg] = f2bf(silu_f(acc[m][n][rr] + bv));
            }
    }
    for (int m = 0; m < 4; ++m)
        for (int n = 0; n < 4; ++n)
            acc[m][n] = (ffrag){0.0f, 0.0f, 0.0f, 0.0f};
    __syncthreads();

    kloop(wn2s, 16, 0);

    for (int n = 0; n < 4; ++n) {
        int cg = w * 64 + n * 16 + ml;
        float bv = b2[cg];
        for (int m = 0; m < 4; ++m)
            for (int rr = 0; rr < 4; ++rr) {
                int rowl = 16 * m + 4 * q + rr;
                int row = rowbase + rowl;
                if (row < N_NODES) {
                    float v = silu_f(acc[m][n][rr] + bv);
                    out[(size_t)row * HD + cg] = nf[(size_t)row * HD + cg] + v;
                }
            }
    }
}

// ---------------------------------------------------------------------------
extern "C" void kernel_launch(void* const* d_in, const int* in_sizes, int n_in,
                              void* d_out, int out_size, void* d_ws, size_t ws_size,
                              hipStream_t stream) {
    const float* nf      = (const float*)d_in[0];
    const float* latt    = (const float*)d_in[1];
    const int*   eidx    = (const int*)d_in[2];
    const int*   e2g     = (const int*)d_in[3];
    const float* fd      = (const float*)d_in[4];
    const float* ln_g    = (const float*)d_in[6];
    const float* ln_b    = (const float*)d_in[7];
    const float* W_e1    = (const float*)d_in[8];
    const float* b_e1    = (const float*)d_in[9];
    const float* W_e2    = (const float*)d_in[10];
    const float* b_e2    = (const float*)d_in[11];
    const float* W_n1    = (const float*)d_in[12];
    const float* b_n1    = (const float*)d_in[13];
    const float* W_n2    = (const float*)d_in[14];
    const float* b_n2    = (const float*)d_in[15];
    float* out = (float*)d_out;

    auto al = [](size_t x) { return (x + 511) & ~(size_t)511; };
    size_t off_h    = 0;                         size_t sz_h    = (size_t)N_NODES * HD * 2;
    size_t off_w1a  = al(off_h + sz_h);          size_t sz_w1a  = (size_t)HD * HD * 2;
    size_t off_w1b  = al(off_w1a + sz_w1a);      size_t sz_w1b  = (size_t)HD * HD * 2;
    size_t off_w1c  = al(off_w1b + sz_w1b);      size_t sz_w1c  = (size_t)KC * HD * 2;
    size_t off_w2   = al(off_w1c + sz_w1c);      size_t sz_w2   = (size_t)HD * HD * 2;
    size_t off_wn1  = al(off_w2 + sz_w2);        size_t sz_wn1  = (size_t)2 * HD * HD * 2;
    size_t off_wn2  = al(off_wn1 + sz_wn1);      size_t sz_wn2  = (size_t)HD * HD * 2;
    size_t off_ha   = al(off_wn2 + sz_wn2);      size_t sz_ha   = (size_t)N_NODES * HD * 2;
    size_t off_hb   = al(off_ha + sz_ha);        size_t sz_hb   = (size_t)N_NODES * HD * 2;
    size_t off_agb  = al(off_hb + sz_hb);        size_t sz_agb  = (size_t)N_NODES * HD * 2;
    size_t off_c32  = al(off_agb + sz_agb);      size_t sz_c32  = (size_t)N_NODES * 4;
    size_t off_cur  = al(off_c32 + sz_c32);      size_t sz_cur  = (size_t)N_NODES * 4;
    size_t off_rp   = al(off_cur + sz_cur);      size_t sz_rp   = (size_t)(N_NODES + 1) * 4;
    size_t off_ebuf = al(off_rp + sz_rp);        size_t sz_ebuf = (size_t)N_EDGES * 4;
    size_t off_agg  = al(off_ebuf + sz_ebuf);    size_t sz_agg  = (size_t)N_NODES * HD * 4;
    size_t need     = off_agg + sz_agg;

    if (ws_size < need) {
        sentinel_kernel<<<(out_size + 255) / 256, 256, 0, stream>>>(out, out_size);
        return;
    }

    char* ws = (char*)d_ws;
    ushort* h     = (ushort*)(ws + off_h);
    ushort* w1a_s = (ushort*)(ws + off_w1a);
    ushort* w1b_s = (ushort*)(ws + off_w1b);
    ushort* w1c_s = (ushort*)(ws + off_w1c);
    ushort* w2s   = (ushort*)(ws + off_w2);
    ushort* wn1s  = (ushort*)(ws + off_wn1);
    ushort* wn2s  = (ushort*)(ws + off_wn2);
    ushort* HA    = (ushort*)(ws + off_ha);
    ushort* HB    = (ushort*)(ws + off_hb);
    ushort* aggb  = (ushort*)(ws + off_agb);
    int*    c32   = (int*)(ws + off_c32);
    int*    cur   = (int*)(ws + off_cur);
    int*    rp    = (int*)(ws + off_rp);
    int*    ebuf  = (int*)(ws + off_ebuf);
    float*  agg   = (float*)(ws + off_agg);

    // prep
    ln_kernel<<<N_NODES, 256, 0, stream>>>(nf, ln_g, ln_b, h);
    wswz_kernel<<<(HD / 32) * NT * 64 / 256, 256, 0, stream>>>(W_e1, w1a_s, HD, 0);
    wswz_kernel<<<(HD / 32) * NT * 64 / 256, 256, 0, stream>>>(W_e1 + (size_t)HD * HD, w1b_s, HD, 0);
    wswz_kernel<<<(KC / 32) * NT * 64 / 256, 256, 0, stream>>>(W_e1, w1c_s, KC, 2);
    wswz_kernel<<<(HD / 32) * NT * 64 / 256, 256, 0, stream>>>(W_e2, w2s, HD, 0);
    wswz_kernel<<<(2 * HD / 32) * NT * 64 / 256, 256, 0, stream>>>(W_n1, wn1s, 2 * HD, 0);
    wswz_kernel<<<(HD / 32) * NT * 64 / 256, 256, 0, stream>>>(W_n2, wn2s, HD, 0);
    hipMemsetAsync(c32, 0, sz_c32, stream);
    hipMemsetAsync(agg, 0, sz_agg, stream);

    // CSR build (edges sorted by src node)
    hist_kernel<<<(N_EDGES + 255) / 256, 256, 0, stream>>>(eidx, c32);
    scan_kernel<<<1, 1024, 0, stream>>>(c32, rp, cur);
    csr_fill<<<(N_EDGES + 255) / 256, 256, 0, stream>>>(eidx, cur, ebuf);

    // node-level hoist: HA = h*W1a, HB = h*W1b
    int nblocks = (N_NODES + 63) / 64;
    hab_gemm<<<dim3(nblocks, 2), 512, 0, stream>>>(h, w1a_s, w1b_s, HA, HB);

    // fused edge MLP (CSR order) -> agg
    edge_mlp<<<N_EDGES / 64, 512, 0, stream>>>(
        HA, HB, w1c_s, w2s, b_e1, b_e2, agg, eidx, e2g, latt, fd, ebuf);

    // scatter-mean divide (deg from CSR)
    aggdiv_kernel<<<(N_NODES * HD) / 256, 256, 0, stream>>>(agg, rp, aggb);

    // fused node MLP
    node_mlp<<<nblocks, 512, 0, stream>>>(h, aggb, wn1s, wn2s, b_n1, b_n2, nf, out);
}